// Round 1
// baseline (409.034 us; speedup 1.0000x reference)
//
#include <hip/hip_runtime.h>

// ---------------------------------------------------------------------------
// MultiQueryAttention: out = softmax_causal((xWq+bq)(xWk+bk)^T * scale) (xWv+bv) Wo + bo
// B=2, S=2048, HIDDEN=2048, HEADS=16 (multi-query: 1 KV head), HEAD_DIM=128
// Pipeline: cvt x->bf16; transpose+cvt weights; MFMA GEMMs (Q,K,V^T); flash attn; O-proj.
// Workspace use: ~67 MB.
// ---------------------------------------------------------------------------

#define HIDDEN 2048
#define NHEADS 16
#define HDIM 128
#define BATCH 2
#define SEQ 2048
#define SCALE_QK 0.08838834764831845f

typedef __attribute__((ext_vector_type(8))) short bfrag;   // 8 bf16 (4 VGPRs)
typedef __attribute__((ext_vector_type(4))) float facc;    // MFMA accumulator
typedef __attribute__((ext_vector_type(4))) short spack4;  // 4 bf16 packed store

__device__ __forceinline__ unsigned short f2bf(float f) {  // f32 -> bf16 RNE
  unsigned int u = __float_as_uint(f);
  u += 0x7fffu + ((u >> 16) & 1u);
  return (unsigned short)(u >> 16);
}

// async global->LDS, 16B per lane. LDS dest is wave-uniform base + lane*16.
__device__ __forceinline__ void gl_lds16(const void* g, void* l) {
  __builtin_amdgcn_global_load_lds(
      (const __attribute__((address_space(1))) void*)g,
      (__attribute__((address_space(3))) void*)l, 16, 0, 0);
}

// ---------------------------------------------------------------------------
// x f32 -> bf16 (vectorized)
__global__ __launch_bounds__(256) void cvt_bf16(const float* __restrict__ in,
                                                short* __restrict__ out, int n4) {
  int i = blockIdx.x * 256 + threadIdx.x;
  if (i >= n4) return;
  float4 v = ((const float4*)in)[i];
  spack4 o = {(short)f2bf(v.x), (short)f2bf(v.y), (short)f2bf(v.z), (short)f2bf(v.w)};
  ((spack4*)out)[i] = o;
}

// W [K][N] f32  ->  WT [N][K] bf16   (32x32 LDS tiles)
__global__ __launch_bounds__(256) void transpose_cvt(const float* __restrict__ W,
                                                     short* __restrict__ WT,
                                                     int K, int N) {
  __shared__ float t[32][33];
  int tx = threadIdx.x & 31, ty = threadIdx.x >> 5;
  int n0 = blockIdx.x * 32, k0 = blockIdx.y * 32;
#pragma unroll
  for (int j = 0; j < 4; ++j)
    t[ty + j * 8][tx] = W[(size_t)(k0 + ty + j * 8) * N + n0 + tx];
  __syncthreads();
#pragma unroll
  for (int j = 0; j < 4; ++j)
    WT[(size_t)(n0 + ty + j * 8) * K + k0 + tx] = (short)f2bf(t[tx][ty + j * 8]);
}

// ---------------------------------------------------------------------------
// GEMM: C[M][N] = A[M][K](bf16) * BT[N][K](bf16)^T + bias[N]
// 128x128 tile, BK=64, 4 waves in 2x2, each wave 4x4 fragments of 16x16x32 MFMA.
// Staging via global_load_lds w=16 with pre-swizzled source; reads XOR-deswizzle.
// MODE 0: bf16 C[row][col]; MODE 1: bf16 C[col][row] (transposed); MODE 2: f32.
template <int MODE>
__global__ __launch_bounds__(256) void gemm128(const short* __restrict__ A,
                                               const short* __restrict__ BT,
                                               const float* __restrict__ bias,
                                               void* __restrict__ Cout,
                                               int M, int N, int K) {
  __shared__ __align__(16) short Al[128 * 64];
  __shared__ __align__(16) short Bl[128 * 64];
  const int tid = threadIdx.x;
  const int w = tid >> 6, l = tid & 63;
  const int wr = w >> 1, wc = w & 1;
  const int l15 = l & 15, l4 = l >> 4;
  const int m0 = blockIdx.x * 128, n0 = blockIdx.y * 128;
  facc acc[4][4] = {};
  const int nkt = K >> 6;
  for (int kt = 0; kt < nkt; ++kt) {
    // stage A and B^T tiles: 1024 chunks of 16B each, swizzled source
#pragma unroll
    for (int it = 0; it < 4; ++it) {
      int bc = (w * 4 + it) * 64;
      int C = bc + l;
      int row = C >> 3, c = C & 7;
      int gofs = kt * 64 + ((c ^ (row & 7)) << 3);
      gl_lds16(A + (size_t)(m0 + row) * K + gofs, &Al[bc * 8]);
      gl_lds16(BT + (size_t)(n0 + row) * K + gofs, &Bl[bc * 8]);
    }
    __syncthreads();
#pragma unroll
    for (int ks = 0; ks < 2; ++ks) {
      bfrag af[4], bf[4];
#pragma unroll
      for (int mt = 0; mt < 4; ++mt) {
        int row = wr * 64 + mt * 16 + l15;
        int c = ks * 4 + l4;
        af[mt] = *(const bfrag*)&Al[row * 64 + ((c ^ (row & 7)) << 3)];
      }
#pragma unroll
      for (int nt = 0; nt < 4; ++nt) {
        int row = wc * 64 + nt * 16 + l15;
        int c = ks * 4 + l4;
        bf[nt] = *(const bfrag*)&Bl[row * 64 + ((c ^ (row & 7)) << 3)];
      }
#pragma unroll
      for (int mt = 0; mt < 4; ++mt)
#pragma unroll
        for (int nt = 0; nt < 4; ++nt)
          acc[mt][nt] = __builtin_amdgcn_mfma_f32_16x16x32_bf16(af[mt], bf[nt],
                                                                acc[mt][nt], 0, 0, 0);
    }
    __syncthreads();
  }
  // epilogue: D[row=(l>>4)*4+r][col=l&15] per fragment
#pragma unroll
  for (int mt = 0; mt < 4; ++mt) {
#pragma unroll
    for (int nt = 0; nt < 4; ++nt) {
#pragma unroll
      for (int r = 0; r < 4; ++r) {
        int row = m0 + wr * 64 + mt * 16 + l4 * 4 + r;
        int col = n0 + wc * 64 + nt * 16 + l15;
        float v = acc[mt][nt][r] + bias[col];
        if (MODE == 0)
          ((unsigned short*)Cout)[(size_t)row * N + col] = f2bf(v);
        else if (MODE == 1)
          ((unsigned short*)Cout)[(size_t)col * M + row] = f2bf(v);
        else
          ((float*)Cout)[(size_t)row * N + col] = v;
      }
    }
  }
}

// ---------------------------------------------------------------------------
// Flash attention (causal, multi-query). Grid: (S/64, HEADS, B), 256 threads.
// Each wave owns 16 q-rows; KV tiles of 32 keys staged in LDS (shared by block).
// Q bf16 [B*S][HIDDEN] (head-major cols), K bf16 [B*S][128], Vt bf16 [128][B*S].
// Output O bf16 [B*S][HIDDEN].
__global__ __launch_bounds__(256) void attn_kernel(const short* __restrict__ Q,
                                                   const short* __restrict__ Kg,
                                                   const short* __restrict__ Vt,
                                                   unsigned short* __restrict__ O) {
  __shared__ __align__(16) short Kl[32 * 128];          // [key][d], swizzled
  __shared__ __align__(16) short Vl[128 * 32];          // [d][key], swizzled
  __shared__ __align__(16) unsigned short Pl[4][16][40];  // per-wave P, padded
  const int tid = threadIdx.x;
  const int w = tid >> 6, l = tid & 63;
  const int l15 = l & 15, l4 = l >> 4;
  const int q0 = blockIdx.x * 64;
  const int h = blockIdx.y;
  const int b = blockIdx.z;

  // Q fragments in registers: A-operand rows = q0 + w*16 + (l&15)
  const int qrow = q0 + w * 16 + l15;
  bfrag aq[4];
#pragma unroll
  for (int kk = 0; kk < 4; ++kk)
    aq[kk] = *(const bfrag*)(Q + (size_t)(b * SEQ + qrow) * HIDDEN + h * HDIM +
                             kk * 32 + l4 * 8);

  facc accO[8] = {};
  float mrow[4], lrow[4];
#pragma unroll
  for (int r = 0; r < 4; ++r) { mrow[r] = -INFINITY; lrow[r] = 0.f; }

  const int nkv = (q0 + 64) >> 5;
  for (int t = 0; t < nkv; ++t) {
    const int kv0 = t << 5;
    // stage K tile [32][128] and Vt tile [128][32], swizzled sources
#pragma unroll
    for (int it = 0; it < 2; ++it) {
      int bc = (w * 2 + it) * 64;
      int C = bc + l;
      {
        int key = C >> 4, c = C & 15;
        gl_lds16(Kg + (size_t)(b * SEQ + kv0 + key) * HDIM + ((c ^ (key & 7)) << 3),
                 &Kl[bc * 8]);
      }
      {
        int d = C >> 2, c = C & 3;
        gl_lds16(Vt + (size_t)d * (BATCH * SEQ) + b * SEQ + kv0 +
                     ((c ^ ((d >> 1) & 3)) << 3),
                 &Vl[bc * 8]);
      }
    }
    __syncthreads();

    // QK^T: two 16-key column tiles, K-dim = D = 128 (4 mfma steps)
    facc accS[2];
#pragma unroll
    for (int ct = 0; ct < 2; ++ct) {
      facc s = {};
#pragma unroll
      for (int kk = 0; kk < 4; ++kk) {
        int key = ct * 16 + l15;
        int c = kk * 4 + l4;
        bfrag bk = *(const bfrag*)&Kl[key * 128 + ((c ^ (key & 7)) << 3)];
        s = __builtin_amdgcn_mfma_f32_16x16x32_bf16(aq[kk], bk, s, 0, 0, 0);
      }
      accS[ct] = s;
    }

    // mask + online softmax (rows (l>>4)*4+r, cols across 16 consecutive lanes)
    float fscale[4];
#pragma unroll
    for (int r = 0; r < 4; ++r) {
      int row = q0 + w * 16 + l4 * 4 + r;
      float sv0 = accS[0][r] * SCALE_QK;
      float sv1 = accS[1][r] * SCALE_QK;
      if (kv0 + l15 > row) sv0 = -INFINITY;
      if (kv0 + 16 + l15 > row) sv1 = -INFINITY;
      float m = fmaxf(sv0, sv1);
#pragma unroll
      for (int off = 1; off < 16; off <<= 1) m = fmaxf(m, __shfl_xor(m, off));
      float mn = fmaxf(mrow[r], m);
      float f = __expf(mrow[r] - mn);
      float p0 = __expf(sv0 - mn);
      float p1 = __expf(sv1 - mn);
      float ps = p0 + p1;
#pragma unroll
      for (int off = 1; off < 16; off <<= 1) ps += __shfl_xor(ps, off);
      lrow[r] = lrow[r] * f + ps;
      mrow[r] = mn;
      fscale[r] = f;
      int prow = l4 * 4 + r;
      Pl[w][prow][l15] = f2bf(p0);
      Pl[w][prow][16 + l15] = f2bf(p1);
    }
    // rescale O accumulator
#pragma unroll
    for (int nt = 0; nt < 8; ++nt)
#pragma unroll
      for (int r = 0; r < 4; ++r) accO[nt][r] *= fscale[r];

    // PV: A = P[16q][32keys] from LDS, B = V[key][d] from Vt tile
    bfrag ap = *(const bfrag*)&Pl[w][l15][l4 * 8];
#pragma unroll
    for (int nt = 0; nt < 8; ++nt) {
      int d = nt * 16 + l15;
      int c = l4 ^ ((d >> 1) & 3);
      bfrag bv = *(const bfrag*)&Vl[d * 32 + c * 8];
      accO[nt] = __builtin_amdgcn_mfma_f32_16x16x32_bf16(ap, bv, accO[nt], 0, 0, 0);
    }
    __syncthreads();
  }

  // finalize: divide by row sum, store bf16
#pragma unroll
  for (int r = 0; r < 4; ++r) {
    float inv = 1.0f / lrow[r];
    int row = q0 + w * 16 + l4 * 4 + r;
#pragma unroll
    for (int nt = 0; nt < 8; ++nt) {
      int col = h * HDIM + nt * 16 + l15;
      O[(size_t)(b * SEQ + row) * HIDDEN + col] = f2bf(accO[nt][r] * inv);
    }
  }
}

// ---------------------------------------------------------------------------
extern "C" void kernel_launch(void* const* d_in, const int* in_sizes, int n_in,
                              void* d_out, int out_size, void* d_ws, size_t ws_size,
                              hipStream_t stream) {
  const float* x = (const float*)d_in[0];
  // d_in[1] = mask (causal, applied analytically)
  const float* Wq = (const float*)d_in[2];
  const float* bq = (const float*)d_in[3];
  const float* Wk = (const float*)d_in[4];
  const float* bk = (const float*)d_in[5];
  const float* Wv = (const float*)d_in[6];
  const float* bv = (const float*)d_in[7];
  const float* Wo = (const float*)d_in[8];
  const float* bo = (const float*)d_in[9];
  float* out = (float*)d_out;

  const size_t MS = (size_t)BATCH * SEQ;  // 4096
  char* ws = (char*)d_ws;
  short* xb = (short*)ws;   ws += MS * HIDDEN * 2;
  short* WqT = (short*)ws;  ws += (size_t)HIDDEN * HIDDEN * 2;
  short* WkT = (short*)ws;  ws += (size_t)HDIM * HIDDEN * 2;
  short* WvT = (short*)ws;  ws += (size_t)HDIM * HIDDEN * 2;
  short* WoT = (short*)ws;  ws += (size_t)HIDDEN * HIDDEN * 2;
  short* Qb = (short*)ws;   ws += MS * HIDDEN * 2;
  short* Kb = (short*)ws;   ws += MS * HDIM * 2;
  short* Vtb = (short*)ws;  ws += (size_t)HDIM * MS * 2;
  short* Ab = (short*)ws;   ws += MS * HIDDEN * 2;

  cvt_bf16<<<(int)(MS * HIDDEN / 4 / 256), 256, 0, stream>>>(x, xb,
                                                             (int)(MS * HIDDEN / 4));
  transpose_cvt<<<dim3(HIDDEN / 32, HIDDEN / 32), 256, 0, stream>>>(Wq, WqT, HIDDEN, HIDDEN);
  transpose_cvt<<<dim3(HDIM / 32, HIDDEN / 32), 256, 0, stream>>>(Wk, WkT, HIDDEN, HDIM);
  transpose_cvt<<<dim3(HDIM / 32, HIDDEN / 32), 256, 0, stream>>>(Wv, WvT, HIDDEN, HDIM);
  transpose_cvt<<<dim3(HIDDEN / 32, HIDDEN / 32), 256, 0, stream>>>(Wo, WoT, HIDDEN, HIDDEN);

  gemm128<0><<<dim3(32, 16), 256, 0, stream>>>(xb, WqT, bq, Qb, (int)MS, HIDDEN, HIDDEN);
  gemm128<0><<<dim3(32, 1), 256, 0, stream>>>(xb, WkT, bk, Kb, (int)MS, HDIM, HIDDEN);
  gemm128<1><<<dim3(32, 1), 256, 0, stream>>>(xb, WvT, bv, Vtb, (int)MS, HDIM, HIDDEN);

  attn_kernel<<<dim3(SEQ / 64, NHEADS, BATCH), 256, 0, stream>>>(Qb, Kb, Vtb,
                                                                 (unsigned short*)Ab);

  gemm128<2><<<dim3(32, 16), 256, 0, stream>>>(Ab, WoT, bo, out, (int)MS, HIDDEN, HIDDEN);
}

// Round 3
// 258.736 us; speedup vs baseline: 1.5809x; 1.5809x over previous
//
#include <hip/hip_runtime.h>

// ---------------------------------------------------------------------------
// MultiQueryAttention: out = softmax_causal((xWq+bq)(xWk+bk)^T * scale) (xWv+bv) Wo + bo
// B=2, S=2048, HIDDEN=2048, HEADS=16 (multi-query: 1 KV head), HEAD_DIM=128
// R2: fix K-tile staging indexing in attn (rows are 128 shorts = 16 chunks, not 8).
// ---------------------------------------------------------------------------

#define HIDDEN 2048
#define NHEADS 16
#define HDIM 128
#define BATCH 2
#define SEQ 2048
#define SCALE_QK 0.08838834764831845f

typedef __attribute__((ext_vector_type(8))) short bfrag;   // 8 bf16 (4 VGPRs)
typedef __attribute__((ext_vector_type(4))) float facc;    // MFMA accumulator
typedef __attribute__((ext_vector_type(4))) short spack4;  // 4 bf16 packed store

__device__ __forceinline__ unsigned short f2bf(float f) {  // f32 -> bf16 RNE
  unsigned int u = __float_as_uint(f);
  u += 0x7fffu + ((u >> 16) & 1u);
  return (unsigned short)(u >> 16);
}

// async global->LDS, 16B per lane. LDS dest is WAVE-UNIFORM base (+lane*16 by HW).
__device__ __forceinline__ void gl_lds16(const void* g, void* l) {
  __builtin_amdgcn_global_load_lds(
      (const __attribute__((address_space(1))) void*)g,
      (__attribute__((address_space(3))) void*)l, 16, 0, 0);
}

// ---------------------------------------------------------------------------
// x f32 -> bf16 (vectorized)
__global__ __launch_bounds__(256) void cvt_bf16(const float* __restrict__ in,
                                                short* __restrict__ out, int n4) {
  int i = blockIdx.x * 256 + threadIdx.x;
  if (i >= n4) return;
  float4 v = ((const float4*)in)[i];
  spack4 o = {(short)f2bf(v.x), (short)f2bf(v.y), (short)f2bf(v.z), (short)f2bf(v.w)};
  ((spack4*)out)[i] = o;
}

// W [K][N] f32  ->  WT [N][K] bf16   (32x32 LDS tiles)
__global__ __launch_bounds__(256) void transpose_cvt(const float* __restrict__ W,
                                                     short* __restrict__ WT,
                                                     int K, int N) {
  __shared__ float t[32][33];
  int tx = threadIdx.x & 31, ty = threadIdx.x >> 5;
  int n0 = blockIdx.x * 32, k0 = blockIdx.y * 32;
#pragma unroll
  for (int j = 0; j < 4; ++j)
    t[ty + j * 8][tx] = W[(size_t)(k0 + ty + j * 8) * N + n0 + tx];
  __syncthreads();
#pragma unroll
  for (int j = 0; j < 4; ++j)
    WT[(size_t)(n0 + ty + j * 8) * K + k0 + tx] = (short)f2bf(t[tx][ty + j * 8]);
}

// ---------------------------------------------------------------------------
// GEMM: C[M][N] = A[M][K](bf16) * BT[N][K](bf16)^T + bias[N]
// 128x128 tile, BK=64, 4 waves 2x2, 4x4 frags of 16x16x32 MFMA each.
// MODE 0: bf16 C[row][col]; MODE 2: f32 C[row][col];
// MODE 3: col<128 -> bf16 Cout[row][col] (K), col>=128 -> bf16 Cout2[(col-128)*M+row] (V^T).
template <int MODE>
__global__ __launch_bounds__(256) void gemm128(const short* __restrict__ A,
                                               const short* __restrict__ BT,
                                               const float* __restrict__ bias,
                                               const float* __restrict__ bias2,
                                               void* __restrict__ Cout,
                                               void* __restrict__ Cout2,
                                               int M, int N, int K) {
  __shared__ __align__(16) short Al[128 * 64];
  __shared__ __align__(16) short Bl[128 * 64];
  const int tid = threadIdx.x;
  const int w = tid >> 6, l = tid & 63;
  const int wr = w >> 1, wc = w & 1;
  const int l15 = l & 15, l4 = l >> 4;
  const int m0 = blockIdx.x * 128, n0 = blockIdx.y * 128;
  facc acc[4][4] = {};
  const int nkt = K >> 6;
  for (int kt = 0; kt < nkt; ++kt) {
#pragma unroll
    for (int it = 0; it < 4; ++it) {
      int bc = (w * 4 + it) * 64;
      int C = bc + l;
      int row = C >> 3, c = C & 7;  // rows of 64 shorts = 8 chunks
      int gofs = kt * 64 + ((c ^ (row & 7)) << 3);
      gl_lds16(A + (size_t)(m0 + row) * K + gofs, &Al[bc * 8]);
      gl_lds16(BT + (size_t)(n0 + row) * K + gofs, &Bl[bc * 8]);
    }
    __syncthreads();
#pragma unroll
    for (int ks = 0; ks < 2; ++ks) {
      bfrag af[4], bf[4];
#pragma unroll
      for (int mt = 0; mt < 4; ++mt) {
        int row = wr * 64 + mt * 16 + l15;
        int c = ks * 4 + l4;
        af[mt] = *(const bfrag*)&Al[row * 64 + ((c ^ (row & 7)) << 3)];
      }
#pragma unroll
      for (int nt = 0; nt < 4; ++nt) {
        int row = wc * 64 + nt * 16 + l15;
        int c = ks * 4 + l4;
        bf[nt] = *(const bfrag*)&Bl[row * 64 + ((c ^ (row & 7)) << 3)];
      }
#pragma unroll
      for (int mt = 0; mt < 4; ++mt)
#pragma unroll
        for (int nt = 0; nt < 4; ++nt)
          acc[mt][nt] = __builtin_amdgcn_mfma_f32_16x16x32_bf16(af[mt], bf[nt],
                                                                acc[mt][nt], 0, 0, 0);
    }
    __syncthreads();
  }
#pragma unroll
  for (int mt = 0; mt < 4; ++mt) {
#pragma unroll
    for (int nt = 0; nt < 4; ++nt) {
#pragma unroll
      for (int r = 0; r < 4; ++r) {
        int row = m0 + wr * 64 + mt * 16 + l4 * 4 + r;
        int col = n0 + wc * 64 + nt * 16 + l15;
        if (MODE == 0) {
          float v = acc[mt][nt][r] + bias[col];
          ((unsigned short*)Cout)[(size_t)row * N + col] = f2bf(v);
        } else if (MODE == 2) {
          float v = acc[mt][nt][r] + bias[col];
          ((float*)Cout)[(size_t)row * N + col] = v;
        } else {  // MODE 3
          if (col < HDIM) {
            float v = acc[mt][nt][r] + bias[col];
            ((unsigned short*)Cout)[(size_t)row * HDIM + col] = f2bf(v);
          } else {
            float v = acc[mt][nt][r] + bias2[col - HDIM];
            ((unsigned short*)Cout2)[(size_t)(col - HDIM) * M + row] = f2bf(v);
          }
        }
      }
    }
  }
}

// ---------------------------------------------------------------------------
// Flash attention, swapped QK^T, causal-paired blocks.
// Grid: (S/128/2=8, HEADS, B), 256 threads (4 waves x 32 q-rows).
// Pass 0 handles q-tile x, pass 1 handles q-tile 15-x -> every block
// does exactly 34 KV-tiles of 64 keys. K,V^T double-buffered in LDS (swizzled).
__global__ __launch_bounds__(256, 1) void attn_kernel(const short* __restrict__ Q,
                                                      const short* __restrict__ Kg,
                                                      const short* __restrict__ Vt,
                                                      unsigned short* __restrict__ O) {
  __shared__ __align__(16) short Kl[2][64 * 128];   // [buf][key][d] swizzled
  __shared__ __align__(16) short Vl[2][128 * 64];   // [buf][d][key] swizzled
  __shared__ __align__(16) char Pl[4][2][2048];     // [wave][qsub] 16x64 bf16 swizzled
  const int tid = threadIdx.x;
  const int w = tid >> 6, l = tid & 63;
  const int l15 = l & 15, l4 = l >> 4;
  const int h = blockIdx.y, b = blockIdx.z;

  // K tile rows are 128 shorts = 16 chunks of 8 (key = C>>4); V tile rows are
  // 64 shorts = 8 chunks (d = C>>3). Source pre-swizzled so LDS stays linear.
#define STAGE_KV(buf, t)                                                         \
  do {                                                                           \
    const int kv0_ = (t) << 6;                                                   \
    _Pragma("unroll") for (int it = 0; it < 4; ++it) {                           \
      int bc = (w * 4 + it) * 64;                                                \
      int C = bc + l;                                                            \
      int key = C >> 4, c = C & 15;                                              \
      gl_lds16(Kg + (size_t)(b * SEQ + kv0_ + key) * HDIM + ((c ^ (key & 7)) << 3), \
               &Kl[buf][bc * 8]);                                                \
    }                                                                            \
    _Pragma("unroll") for (int it = 0; it < 4; ++it) {                           \
      int bc = (w * 4 + it) * 64;                                                \
      int C = bc + l;                                                            \
      int d = C >> 3, c = C & 7;                                                 \
      gl_lds16(Vt + (size_t)d * (BATCH * SEQ) + b * SEQ + kv0_ + ((c ^ (d & 7)) << 3), \
               &Vl[buf][bc * 8]);                                                \
    }                                                                            \
  } while (0)

  for (int pass = 0; pass < 2; ++pass) {
    const int qtile = (pass == 0) ? (int)blockIdx.x : 15 - (int)blockIdx.x;
    const int q0 = qtile * 128;

    // Q fragments (B-operand: col=q=l15, k contiguous): 2 q-subtiles x 4 k-chunks
    bfrag aq[2][4];
#pragma unroll
    for (int s = 0; s < 2; ++s)
#pragma unroll
      for (int kk = 0; kk < 4; ++kk)
        aq[s][kk] = *(const bfrag*)(Q + (size_t)(b * SEQ + q0 + w * 32 + s * 16 + l15) * HIDDEN +
                                    h * HDIM + kk * 32 + l4 * 8);

    facc accO[2][8] = {};
    float mrow[2] = {-INFINITY, -INFINITY}, lrow[2] = {0.f, 0.f};
    const int nkv = (q0 + 128) >> 6;

    STAGE_KV(0, 0);
    __syncthreads();

    for (int t = 0; t < nkv; ++t) {
      const int cur = t & 1;
      if (t + 1 < nkv) STAGE_KV(cur ^ 1, t + 1);
      const int kv0 = t << 6;

      // S^T = K * Q^T : A-frag = K (row=key=l15), B-frag = Q (col=q=l15)
      facc sac[2][4] = {};
#pragma unroll
      for (int kt = 0; kt < 4; ++kt) {
#pragma unroll
        for (int kk = 0; kk < 4; ++kk) {
          int key = kt * 16 + l15;
          int c = kk * 4 + l4;
          bfrag ak = *(const bfrag*)&Kl[cur][key * 128 + ((c ^ (key & 7)) << 3)];
          sac[0][kt] = __builtin_amdgcn_mfma_f32_16x16x32_bf16(ak, aq[0][kk], sac[0][kt], 0, 0, 0);
          sac[1][kt] = __builtin_amdgcn_mfma_f32_16x16x32_bf16(ak, aq[1][kk], sac[1][kt], 0, 0, 0);
        }
      }

      // online softmax per q-subtile; lane holds 16 S values for q = l15
      float fr[2][4];
#pragma unroll
      for (int s = 0; s < 2; ++s) {
        const int qg = q0 + w * 32 + s * 16 + l15;
        const bool needmask = (kv0 + 63 > q0 + w * 32 + s * 16);
        float p[4][4];
        float mt = -INFINITY;
#pragma unroll
        for (int kt = 0; kt < 4; ++kt)
#pragma unroll
          for (int r = 0; r < 4; ++r) {
            float v = sac[s][kt][r] * SCALE_QK;
            if (needmask) {
              int keyg = kv0 + kt * 16 + l4 * 4 + r;
              v = (keyg <= qg) ? v : -INFINITY;
            }
            p[kt][r] = v;
            mt = fmaxf(mt, v);
          }
        mt = fmaxf(mt, __shfl_xor(mt, 16));
        mt = fmaxf(mt, __shfl_xor(mt, 32));
        float mn = fmaxf(mrow[s], mt);
        float f = __expf(mrow[s] - mn);
        mrow[s] = mn;
        float ps = 0.f;
#pragma unroll
        for (int kt = 0; kt < 4; ++kt)
#pragma unroll
          for (int r = 0; r < 4; ++r) {
            p[kt][r] = __expf(p[kt][r] - mn);
            ps += p[kt][r];
          }
        ps += __shfl_xor(ps, 16);
        ps += __shfl_xor(ps, 32);
        lrow[s] = lrow[s] * f + ps;
#pragma unroll
        for (int r = 0; r < 4; ++r) fr[s][r] = __shfl(f, l4 * 4 + r);

        // pack P^T -> P[q][key] bf16 in per-wave LDS (swizzled rows)
        char* pw = &Pl[w][s][0];
#pragma unroll
        for (int kt = 0; kt < 4; ++kt)
#pragma unroll
          for (int rp = 0; rp < 2; ++rp) {
            unsigned int u = ((unsigned int)f2bf(p[kt][2 * rp + 1]) << 16) | f2bf(p[kt][2 * rp]);
            int byte = (l15 * 128 + (kt * 16 + l4 * 4 + 2 * rp) * 2) ^ ((l15 & 7) << 4);
            *(unsigned int*)(pw + byte) = u;
          }
        // rescale O accumulator (rows q = l4*4+r)
#pragma unroll
        for (int nt = 0; nt < 8; ++nt)
#pragma unroll
          for (int r = 0; r < 4; ++r) accO[s][nt][r] *= fr[s][r];
      }

      // PV: A = P[q][key] (row=q=l15), B = V^T row d (col=d=l15, k=key contiguous)
#pragma unroll
      for (int kc = 0; kc < 2; ++kc) {
        bfrag pa0 = *(const bfrag*)(&Pl[w][0][0] +
                                    ((l15 * 128 + (kc * 32 + l4 * 8) * 2) ^ ((l15 & 7) << 4)));
        bfrag pa1 = *(const bfrag*)(&Pl[w][1][0] +
                                    ((l15 * 128 + (kc * 32 + l4 * 8) * 2) ^ ((l15 & 7) << 4)));
#pragma unroll
        for (int nt = 0; nt < 8; ++nt) {
          int d = nt * 16 + l15;
          int cslot = (kc * 4 + l4) ^ (d & 7);
          bfrag bv = *(const bfrag*)&Vl[cur][d * 64 + (cslot << 3)];
          accO[0][nt] = __builtin_amdgcn_mfma_f32_16x16x32_bf16(pa0, bv, accO[0][nt], 0, 0, 0);
          accO[1][nt] = __builtin_amdgcn_mfma_f32_16x16x32_bf16(pa1, bv, accO[1][nt], 0, 0, 0);
        }
      }
      __syncthreads();
    }

    // epilogue: O rows q = l4*4+r, cols d = nt*16+l15
#pragma unroll
    for (int s = 0; s < 2; ++s) {
      float inv = 1.f / lrow[s];
#pragma unroll
      for (int r = 0; r < 4; ++r) {
        float invr = __shfl(inv, l4 * 4 + r);
        int row = q0 + w * 32 + s * 16 + l4 * 4 + r;
#pragma unroll
        for (int nt = 0; nt < 8; ++nt)
          O[(size_t)(b * SEQ + row) * HIDDEN + h * HDIM + nt * 16 + l15] =
              f2bf(accO[s][nt][r] * invr);
      }
    }
  }
#undef STAGE_KV
}

// ---------------------------------------------------------------------------
extern "C" void kernel_launch(void* const* d_in, const int* in_sizes, int n_in,
                              void* d_out, int out_size, void* d_ws, size_t ws_size,
                              hipStream_t stream) {
  const float* x = (const float*)d_in[0];
  // d_in[1] = mask (causal, applied analytically)
  const float* Wq = (const float*)d_in[2];
  const float* bq = (const float*)d_in[3];
  const float* Wk = (const float*)d_in[4];
  const float* bk = (const float*)d_in[5];
  const float* Wv = (const float*)d_in[6];
  const float* bv = (const float*)d_in[7];
  const float* Wo = (const float*)d_in[8];
  const float* bo = (const float*)d_in[9];
  float* out = (float*)d_out;

  const size_t MS = (size_t)BATCH * SEQ;  // 4096
  char* ws = (char*)d_ws;
  short* xb = (short*)ws;    ws += MS * HIDDEN * 2;
  short* WqT = (short*)ws;   ws += (size_t)HIDDEN * HIDDEN * 2;
  short* WkvT = (short*)ws;  ws += (size_t)2 * HDIM * HIDDEN * 2;  // [Wk;Wv] stacked
  short* WoT = (short*)ws;   ws += (size_t)HIDDEN * HIDDEN * 2;
  short* Qb = (short*)ws;    ws += MS * HIDDEN * 2;
  short* Kb = (short*)ws;    ws += MS * HDIM * 2;
  short* Vtb = (short*)ws;   ws += (size_t)HDIM * MS * 2;
  short* Ab = (short*)ws;    ws += MS * HIDDEN * 2;

  cvt_bf16<<<(int)(MS * HIDDEN / 4 / 256), 256, 0, stream>>>(x, xb,
                                                             (int)(MS * HIDDEN / 4));
  transpose_cvt<<<dim3(HIDDEN / 32, HIDDEN / 32), 256, 0, stream>>>(Wq, WqT, HIDDEN, HIDDEN);
  transpose_cvt<<<dim3(HDIM / 32, HIDDEN / 32), 256, 0, stream>>>(Wk, WkvT, HIDDEN, HDIM);
  transpose_cvt<<<dim3(HDIM / 32, HIDDEN / 32), 256, 0, stream>>>(Wv, WkvT + (size_t)HDIM * HIDDEN,
                                                                  HIDDEN, HDIM);
  transpose_cvt<<<dim3(HIDDEN / 32, HIDDEN / 32), 256, 0, stream>>>(Wo, WoT, HIDDEN, HIDDEN);

  gemm128<0><<<dim3(32, 16), 256, 0, stream>>>(xb, WqT, bq, bq, Qb, nullptr,
                                               (int)MS, HIDDEN, HIDDEN);
  gemm128<3><<<dim3(32, 2), 256, 0, stream>>>(xb, WkvT, bk, bv, Kb, Vtb,
                                              (int)MS, 2 * HDIM, HIDDEN);

  attn_kernel<<<dim3(8, NHEADS, BATCH), 256, 0, stream>>>(Qb, Kb, Vtb,
                                                          (unsigned short*)Ab);

  gemm128<2><<<dim3(32, 16), 256, 0, stream>>>(Ab, WoT, bo, bo, out, nullptr,
                                               (int)MS, HIDDEN, HIDDEN);
}

// Round 4
// 243.917 us; speedup vs baseline: 1.6769x; 1.0608x over previous
//
#include <hip/hip_runtime.h>

// ---------------------------------------------------------------------------
// MultiQueryAttention: out = softmax_causal((xWq+bq)(xWk+bk)^T * scale) (xWv+bv) Wo + bo
// B=2, S=2048, HIDDEN=2048, HEADS=16 (multi-query: 1 KV head), HEAD_DIM=128
// R3: attn -> 8 waves x 16 q-rows (2 waves/SIMD TLP), QK^T dep-dist 4, exp2
//     pre-scale, setprio around MFMA; fused QKV projection (one 2304-col GEMM).
// ---------------------------------------------------------------------------

#define HIDDEN 2048
#define NHEADS 16
#define HDIM 128
#define BATCH 2
#define SEQ 2048
// SCALE_QK * log2(e): softmax computed in base-2 (exp2), exactly equivalent.
#define SCALE_L2E 0.1275258653864023f

typedef __attribute__((ext_vector_type(8))) short bfrag;   // 8 bf16 (4 VGPRs)
typedef __attribute__((ext_vector_type(4))) float facc;    // MFMA accumulator
typedef __attribute__((ext_vector_type(4))) short spack4;  // 4 bf16 packed store

__device__ __forceinline__ unsigned short f2bf(float f) {  // f32 -> bf16 RNE
  unsigned int u = __float_as_uint(f);
  u += 0x7fffu + ((u >> 16) & 1u);
  return (unsigned short)(u >> 16);
}

// async global->LDS, 16B per lane. LDS dest is WAVE-UNIFORM base (+lane*16 by HW).
__device__ __forceinline__ void gl_lds16(const void* g, void* l) {
  __builtin_amdgcn_global_load_lds(
      (const __attribute__((address_space(1))) void*)g,
      (__attribute__((address_space(3))) void*)l, 16, 0, 0);
}

// ---------------------------------------------------------------------------
// x f32 -> bf16 (vectorized)
__global__ __launch_bounds__(256) void cvt_bf16(const float* __restrict__ in,
                                                short* __restrict__ out, int n4) {
  int i = blockIdx.x * 256 + threadIdx.x;
  if (i >= n4) return;
  float4 v = ((const float4*)in)[i];
  spack4 o = {(short)f2bf(v.x), (short)f2bf(v.y), (short)f2bf(v.z), (short)f2bf(v.w)};
  ((spack4*)out)[i] = o;
}

// W [K][N] f32  ->  WT [N][K] bf16   (32x32 LDS tiles)
__global__ __launch_bounds__(256) void transpose_cvt(const float* __restrict__ W,
                                                     short* __restrict__ WT,
                                                     int K, int N) {
  __shared__ float t[32][33];
  int tx = threadIdx.x & 31, ty = threadIdx.x >> 5;
  int n0 = blockIdx.x * 32, k0 = blockIdx.y * 32;
#pragma unroll
  for (int j = 0; j < 4; ++j)
    t[ty + j * 8][tx] = W[(size_t)(k0 + ty + j * 8) * N + n0 + tx];
  __syncthreads();
#pragma unroll
  for (int j = 0; j < 4; ++j)
    WT[(size_t)(n0 + ty + j * 8) * K + k0 + tx] = (short)f2bf(t[tx][ty + j * 8]);
}

// ---------------------------------------------------------------------------
// Shared GEMM main loop: 128x128 tile, BK=64, 4 waves 2x2, 4x4 frags 16x16x32.
#define GEMM_MAIN_LOOP(A, BT, Kdim)                                            \
  facc acc[4][4] = {};                                                         \
  const int nkt = (Kdim) >> 6;                                                 \
  for (int kt = 0; kt < nkt; ++kt) {                                           \
    _Pragma("unroll") for (int it = 0; it < 4; ++it) {                         \
      int bc = (w * 4 + it) * 64;                                              \
      int C = bc + l;                                                          \
      int row = C >> 3, c = C & 7;                                             \
      int gofs = kt * 64 + ((c ^ (row & 7)) << 3);                             \
      gl_lds16((A) + (size_t)(m0 + row) * (Kdim) + gofs, &Al[bc * 8]);         \
      gl_lds16((BT) + (size_t)(n0 + row) * (Kdim) + gofs, &Bl[bc * 8]);        \
    }                                                                          \
    __syncthreads();                                                           \
    _Pragma("unroll") for (int ks = 0; ks < 2; ++ks) {                         \
      bfrag af[4], bf[4];                                                      \
      _Pragma("unroll") for (int mt = 0; mt < 4; ++mt) {                       \
        int row = wr * 64 + mt * 16 + l15;                                     \
        int c = ks * 4 + l4;                                                   \
        af[mt] = *(const bfrag*)&Al[row * 64 + ((c ^ (row & 7)) << 3)];        \
      }                                                                        \
      _Pragma("unroll") for (int nt = 0; nt < 4; ++nt) {                       \
        int row = wc * 64 + nt * 16 + l15;                                     \
        int c = ks * 4 + l4;                                                   \
        bf[nt] = *(const bfrag*)&Bl[row * 64 + ((c ^ (row & 7)) << 3)];        \
      }                                                                        \
      _Pragma("unroll") for (int mt = 0; mt < 4; ++mt)                         \
          _Pragma("unroll") for (int nt = 0; nt < 4; ++nt)                     \
              acc[mt][nt] = __builtin_amdgcn_mfma_f32_16x16x32_bf16(           \
                  af[mt], bf[nt], acc[mt][nt], 0, 0, 0);                       \
    }                                                                          \
    __syncthreads();                                                           \
  }

// Fused QKV projection: BT = [Wq^T; Wk^T; Wv^T] (2304 rows). Grid (M/128, 18).
// cols [0,2048) -> Qb row-major; [2048,2176) -> Kb; [2176,2304) -> Vtb transposed.
__global__ __launch_bounds__(256) void gemm_qkv(const short* __restrict__ A,
                                                const short* __restrict__ BT,
                                                const float* __restrict__ bq,
                                                const float* __restrict__ bk,
                                                const float* __restrict__ bv,
                                                unsigned short* __restrict__ Qb,
                                                unsigned short* __restrict__ Kb,
                                                unsigned short* __restrict__ Vtb,
                                                int M, int K) {
  __shared__ __align__(16) short Al[128 * 64];
  __shared__ __align__(16) short Bl[128 * 64];
  const int tid = threadIdx.x;
  const int w = tid >> 6, l = tid & 63;
  const int wr = w >> 1, wc = w & 1;
  const int l15 = l & 15, l4 = l >> 4;
  const int m0 = blockIdx.x * 128, n0 = blockIdx.y * 128;
  GEMM_MAIN_LOOP(A, BT, K)
#pragma unroll
  for (int mt = 0; mt < 4; ++mt) {
#pragma unroll
    for (int nt = 0; nt < 4; ++nt) {
#pragma unroll
      for (int r = 0; r < 4; ++r) {
        int row = m0 + wr * 64 + mt * 16 + l4 * 4 + r;
        int col = n0 + wc * 64 + nt * 16 + l15;
        if (col < HIDDEN) {
          Qb[(size_t)row * HIDDEN + col] = f2bf(acc[mt][nt][r] + bq[col]);
        } else if (col < HIDDEN + HDIM) {
          int lc = col - HIDDEN;
          Kb[(size_t)row * HDIM + lc] = f2bf(acc[mt][nt][r] + bk[lc]);
        } else {
          int lc = col - HIDDEN - HDIM;
          Vtb[(size_t)lc * M + row] = f2bf(acc[mt][nt][r] + bv[lc]);
        }
      }
    }
  }
}

// O-projection: f32 output C[row][col] = A*BT^T + bias.
__global__ __launch_bounds__(256) void gemm_out(const short* __restrict__ A,
                                                const short* __restrict__ BT,
                                                const float* __restrict__ bias,
                                                float* __restrict__ Cout,
                                                int M, int N, int K) {
  __shared__ __align__(16) short Al[128 * 64];
  __shared__ __align__(16) short Bl[128 * 64];
  const int tid = threadIdx.x;
  const int w = tid >> 6, l = tid & 63;
  const int wr = w >> 1, wc = w & 1;
  const int l15 = l & 15, l4 = l >> 4;
  const int m0 = blockIdx.x * 128, n0 = blockIdx.y * 128;
  GEMM_MAIN_LOOP(A, BT, K)
#pragma unroll
  for (int mt = 0; mt < 4; ++mt)
#pragma unroll
    for (int nt = 0; nt < 4; ++nt)
#pragma unroll
      for (int r = 0; r < 4; ++r) {
        int row = m0 + wr * 64 + mt * 16 + l4 * 4 + r;
        int col = n0 + wc * 64 + nt * 16 + l15;
        Cout[(size_t)row * N + col] = acc[mt][nt][r] + bias[col];
      }
}

// ---------------------------------------------------------------------------
// Flash attention, swapped QK^T, causal-paired blocks, 8 waves x 16 q-rows.
// Grid: (8, HEADS, B), 512 threads. Pass 0: q-tile x; pass 1: q-tile 15-x
// -> every block does exactly 34 KV-tiles of 64 keys. K,V^T dbuf in LDS.
__global__ __launch_bounds__(512, 1) void attn_kernel(const short* __restrict__ Q,
                                                      const short* __restrict__ Kg,
                                                      const short* __restrict__ Vt,
                                                      unsigned short* __restrict__ O) {
  __shared__ __align__(16) short Kl[2][64 * 128];  // [buf][key][d] swizzled
  __shared__ __align__(16) short Vl[2][128 * 64];  // [buf][d][key] swizzled
  __shared__ __align__(16) char Pl[8][2048];       // per-wave 16q x 64k bf16 swizzled
  const int tid = threadIdx.x;
  const int w = tid >> 6, l = tid & 63;
  const int l15 = l & 15, l4 = l >> 4;
  const int h = blockIdx.y, b = blockIdx.z;

  // K tile: 1024 chunks of 16B, rows of 16 chunks (key=C>>4). V tile: rows of
  // 8 chunks (d=C>>3). 512 threads -> 2 chunks each per tile. Source
  // pre-swizzled (involution c^=row&7) so LDS stays linear for gl_lds.
#define STAGE_KV(buf, t)                                                            \
  do {                                                                              \
    const int kv0_ = (t) << 6;                                                      \
    _Pragma("unroll") for (int it = 0; it < 2; ++it) {                              \
      int bc = (w * 2 + it) * 64;                                                   \
      int C = bc + l;                                                               \
      int key = C >> 4, c = C & 15;                                                 \
      gl_lds16(Kg + (size_t)(b * SEQ + kv0_ + key) * HDIM + ((c ^ (key & 7)) << 3), \
               &Kl[buf][bc * 8]);                                                   \
    }                                                                               \
    _Pragma("unroll") for (int it = 0; it < 2; ++it) {                              \
      int bc = (w * 2 + it) * 64;                                                   \
      int C = bc + l;                                                               \
      int d = C >> 3, c = C & 7;                                                    \
      gl_lds16(Vt + (size_t)d * (BATCH * SEQ) + b * SEQ + kv0_ + ((c ^ (d & 7)) << 3), \
               &Vl[buf][bc * 8]);                                                   \
    }                                                                               \
  } while (0)

  for (int pass = 0; pass < 2; ++pass) {
    const int qtile = (pass == 0) ? (int)blockIdx.x : 15 - (int)blockIdx.x;
    const int q0 = qtile * 128;
    const int qw = q0 + w * 16;  // this wave's 16 q-rows [qw, qw+16)

    // Q fragments (B-operand: col=q=l15, k contiguous): 4 k-chunks of 32
    bfrag aq[4];
#pragma unroll
    for (int kk = 0; kk < 4; ++kk)
      aq[kk] = *(const bfrag*)(Q + (size_t)(b * SEQ + qw + l15) * HIDDEN +
                               h * HDIM + kk * 32 + l4 * 8);

    facc accO[8] = {};
    float mrow = -INFINITY, lrow = 0.f;
    const int nkv = (q0 + 128) >> 6;

    STAGE_KV(0, 0);
    __syncthreads();

    for (int t = 0; t < nkv; ++t) {
      const int cur = t & 1;
      if (t + 1 < nkv) STAGE_KV(cur ^ 1, t + 1);
      const int kv0 = t << 6;

      // S^T = K * Q^T : A-frag = K (row=key=l15), B-frag = Q (col=q=l15).
      // kk outer / kt inner -> MFMA dep distance 4 per sac chain.
      facc sac[4] = {};
      __builtin_amdgcn_s_setprio(1);
#pragma unroll
      for (int kk = 0; kk < 4; ++kk) {
        int c = kk * 4 + l4;
#pragma unroll
        for (int kt = 0; kt < 4; ++kt) {
          int key = kt * 16 + l15;
          bfrag ak = *(const bfrag*)&Kl[cur][key * 128 + ((c ^ (key & 7)) << 3)];
          sac[kt] = __builtin_amdgcn_mfma_f32_16x16x32_bf16(ak, aq[kk], sac[kt], 0, 0, 0);
        }
      }
      __builtin_amdgcn_s_setprio(0);

      // online softmax (base-2): lane holds 16 S values for q = l15
      const int qg = qw + l15;
      const bool needmask = (kv0 + 63 > qw);
      float p[4][4];
      float mt = -INFINITY;
#pragma unroll
      for (int kt = 0; kt < 4; ++kt)
#pragma unroll
        for (int r = 0; r < 4; ++r) {
          float v = sac[kt][r] * SCALE_L2E;
          if (needmask) {
            int keyg = kv0 + kt * 16 + l4 * 4 + r;
            v = (keyg <= qg) ? v : -INFINITY;
          }
          p[kt][r] = v;
          mt = fmaxf(mt, v);
        }
      mt = fmaxf(mt, __shfl_xor(mt, 16));
      mt = fmaxf(mt, __shfl_xor(mt, 32));
      float mn = fmaxf(mrow, mt);
      float f = exp2f(mrow - mn);
      mrow = mn;
      float ps = 0.f;
#pragma unroll
      for (int kt = 0; kt < 4; ++kt)
#pragma unroll
        for (int r = 0; r < 4; ++r) {
          p[kt][r] = exp2f(p[kt][r] - mn);
          ps += p[kt][r];
        }
      ps += __shfl_xor(ps, 16);
      ps += __shfl_xor(ps, 32);
      lrow = lrow * f + ps;
      float fr[4];
#pragma unroll
      for (int r = 0; r < 4; ++r) fr[r] = __shfl(f, l4 * 4 + r);

      // pack P^T -> P[q][key] bf16 in per-wave LDS (swizzled rows)
      char* pw = &Pl[w][0];
#pragma unroll
      for (int kt = 0; kt < 4; ++kt)
#pragma unroll
        for (int rp = 0; rp < 2; ++rp) {
          unsigned int u = ((unsigned int)f2bf(p[kt][2 * rp + 1]) << 16) | f2bf(p[kt][2 * rp]);
          int byte = (l15 * 128 + (kt * 16 + l4 * 4 + 2 * rp) * 2) ^ ((l15 & 7) << 4);
          *(unsigned int*)(pw + byte) = u;
        }
      // rescale O accumulator (rows q = l4*4+r)
#pragma unroll
      for (int nt = 0; nt < 8; ++nt)
#pragma unroll
        for (int r = 0; r < 4; ++r) accO[nt][r] *= fr[r];

      // PV: A = P[q][key] (row=q=l15), B = V^T row d (col=d=l15, k=key contig)
      __builtin_amdgcn_s_setprio(1);
#pragma unroll
      for (int kc = 0; kc < 2; ++kc) {
        bfrag pa = *(const bfrag*)(&Pl[w][0] +
                                   ((l15 * 128 + (kc * 32 + l4 * 8) * 2) ^ ((l15 & 7) << 4)));
#pragma unroll
        for (int nt = 0; nt < 8; ++nt) {
          int d = nt * 16 + l15;
          int cslot = (kc * 4 + l4) ^ (d & 7);
          bfrag bv = *(const bfrag*)&Vl[cur][d * 64 + (cslot << 3)];
          accO[nt] = __builtin_amdgcn_mfma_f32_16x16x32_bf16(pa, bv, accO[nt], 0, 0, 0);
        }
      }
      __builtin_amdgcn_s_setprio(0);
      __syncthreads();
    }

    // epilogue: O rows q = l4*4+r, cols d = nt*16+l15
    float inv = 1.f / lrow;
#pragma unroll
    for (int r = 0; r < 4; ++r) {
      float invr = __shfl(inv, l4 * 4 + r);
      int row = qw + l4 * 4 + r;
#pragma unroll
      for (int nt = 0; nt < 8; ++nt)
        O[(size_t)(b * SEQ + row) * HIDDEN + h * HDIM + nt * 16 + l15] =
            f2bf(accO[nt][r] * invr);
    }
  }
#undef STAGE_KV
}

// ---------------------------------------------------------------------------
extern "C" void kernel_launch(void* const* d_in, const int* in_sizes, int n_in,
                              void* d_out, int out_size, void* d_ws, size_t ws_size,
                              hipStream_t stream) {
  const float* x = (const float*)d_in[0];
  // d_in[1] = mask (causal, applied analytically)
  const float* Wq = (const float*)d_in[2];
  const float* bq = (const float*)d_in[3];
  const float* Wk = (const float*)d_in[4];
  const float* bk = (const float*)d_in[5];
  const float* Wv = (const float*)d_in[6];
  const float* bv = (const float*)d_in[7];
  const float* Wo = (const float*)d_in[8];
  const float* bo = (const float*)d_in[9];
  float* out = (float*)d_out;

  const size_t MS = (size_t)BATCH * SEQ;  // 4096
  char* ws = (char*)d_ws;
  short* xb = (short*)ws;      ws += MS * HIDDEN * 2;
  short* WqkvT = (short*)ws;   ws += (size_t)(HIDDEN + 2 * HDIM) * HIDDEN * 2;  // 2304 rows
  short* WoT = (short*)ws;     ws += (size_t)HIDDEN * HIDDEN * 2;
  short* Qb = (short*)ws;      ws += MS * HIDDEN * 2;
  short* Kb = (short*)ws;      ws += MS * HDIM * 2;
  short* Vtb = (short*)ws;     ws += (size_t)HDIM * MS * 2;
  short* Ab = (short*)ws;      ws += MS * HIDDEN * 2;

  cvt_bf16<<<(int)(MS * HIDDEN / 4 / 256), 256, 0, stream>>>(x, xb,
                                                             (int)(MS * HIDDEN / 4));
  transpose_cvt<<<dim3(HIDDEN / 32, HIDDEN / 32), 256, 0, stream>>>(Wq, WqkvT, HIDDEN, HIDDEN);
  transpose_cvt<<<dim3(HDIM / 32, HIDDEN / 32), 256, 0, stream>>>(
      Wk, WqkvT + (size_t)HIDDEN * HIDDEN, HIDDEN, HDIM);
  transpose_cvt<<<dim3(HDIM / 32, HIDDEN / 32), 256, 0, stream>>>(
      Wv, WqkvT + (size_t)(HIDDEN + HDIM) * HIDDEN, HIDDEN, HDIM);
  transpose_cvt<<<dim3(HIDDEN / 32, HIDDEN / 32), 256, 0, stream>>>(Wo, WoT, HIDDEN, HIDDEN);

  gemm_qkv<<<dim3(32, 18), 256, 0, stream>>>(xb, WqkvT, bq, bk, bv,
                                             (unsigned short*)Qb, (unsigned short*)Kb,
                                             (unsigned short*)Vtb, (int)MS, HIDDEN);

  attn_kernel<<<dim3(8, NHEADS, BATCH), 512, 0, stream>>>(Qb, Kb, Vtb,
                                                          (unsigned short*)Ab);

  gemm_out<<<dim3(32, 16), 256, 0, stream>>>(Ab, WoT, bo, out, (int)MS, HIDDEN, HIDDEN);
}

// Round 5
// 229.678 us; speedup vs baseline: 1.7809x; 1.0620x over previous
//
#include <hip/hip_runtime.h>

// ---------------------------------------------------------------------------
// MultiQueryAttention: out = softmax_causal((xWq+bq)(xWk+bk)^T * scale) (xWv+bv) Wo + bo
// B=2, S=2048, HIDDEN=2048, HEADS=16 (multi-query: 1 KV head), HEAD_DIM=128
// R4: 2-phase pipelined GEMMs (double-buffered LDS, stage-next-before-compute,
//     one barrier per K-step) + setprio; merged transpose launches.
// ---------------------------------------------------------------------------

#define HIDDEN 2048
#define NHEADS 16
#define HDIM 128
#define BATCH 2
#define SEQ 2048
// SCALE_QK * log2(e): softmax computed in base-2 (exp2), exactly equivalent.
#define SCALE_L2E 0.1275258653864023f

typedef __attribute__((ext_vector_type(8))) short bfrag;   // 8 bf16 (4 VGPRs)
typedef __attribute__((ext_vector_type(4))) float facc;    // MFMA accumulator
typedef __attribute__((ext_vector_type(4))) short spack4;  // 4 bf16 packed store

__device__ __forceinline__ unsigned short f2bf(float f) {  // f32 -> bf16 RNE
  unsigned int u = __float_as_uint(f);
  u += 0x7fffu + ((u >> 16) & 1u);
  return (unsigned short)(u >> 16);
}

// async global->LDS, 16B per lane. LDS dest is WAVE-UNIFORM base (+lane*16 by HW).
__device__ __forceinline__ void gl_lds16(const void* g, void* l) {
  __builtin_amdgcn_global_load_lds(
      (const __attribute__((address_space(1))) void*)g,
      (__attribute__((address_space(3))) void*)l, 16, 0, 0);
}

// ---------------------------------------------------------------------------
// x f32 -> bf16 (vectorized)
__global__ __launch_bounds__(256) void cvt_bf16(const float* __restrict__ in,
                                                short* __restrict__ out, int n4) {
  int i = blockIdx.x * 256 + threadIdx.x;
  if (i >= n4) return;
  float4 v = ((const float4*)in)[i];
  spack4 o = {(short)f2bf(v.x), (short)f2bf(v.y), (short)f2bf(v.z), (short)f2bf(v.w)};
  ((spack4*)out)[i] = o;
}

// Two weights per launch (blockIdx.z picks): W [K][N] f32 -> WT [N][K] bf16.
__global__ __launch_bounds__(256) void transpose_cvt2(const float* __restrict__ W0,
                                                      short* __restrict__ T0,
                                                      const float* __restrict__ W1,
                                                      short* __restrict__ T1,
                                                      int K, int N) {
  const float* W = blockIdx.z ? W1 : W0;
  short* WT = blockIdx.z ? T1 : T0;
  __shared__ float t[32][33];
  int tx = threadIdx.x & 31, ty = threadIdx.x >> 5;
  int n0 = blockIdx.x * 32, k0 = blockIdx.y * 32;
#pragma unroll
  for (int j = 0; j < 4; ++j)
    t[ty + j * 8][tx] = W[(size_t)(k0 + ty + j * 8) * N + n0 + tx];
  __syncthreads();
#pragma unroll
  for (int j = 0; j < 4; ++j)
    WT[(size_t)(n0 + ty + j * 8) * K + k0 + tx] = (short)f2bf(t[tx][ty + j * 8]);
}

// ---------------------------------------------------------------------------
// 2-phase pipelined GEMM main loop: 128x128 tile, BK=64, double-buffered LDS.
// Issue next K-step's global_load_lds BEFORE computing current -> the barrier's
// vmcnt drain overlaps the 32-MFMA compute phase instead of serializing.
#define GEMM_STAGE(buf, kt, A, BT, Kdim)                                       \
  _Pragma("unroll") for (int it = 0; it < 4; ++it) {                           \
    int bc = (w * 4 + it) * 64;                                                \
    int C = bc + l;                                                            \
    int row = C >> 3, c = C & 7;                                               \
    int gofs = (kt) * 64 + ((c ^ (row & 7)) << 3);                             \
    gl_lds16((A) + (size_t)(m0 + row) * (Kdim) + gofs, &Al[buf][bc * 8]);      \
    gl_lds16((BT) + (size_t)(n0 + row) * (Kdim) + gofs, &Bl[buf][bc * 8]);     \
  }

#define GEMM_PIPE_LOOP(A, BT, Kdim)                                            \
  facc acc[4][4] = {};                                                         \
  const int nkt = (Kdim) >> 6;                                                 \
  GEMM_STAGE(0, 0, A, BT, Kdim)                                                \
  __syncthreads();                                                             \
  for (int kt = 0; kt < nkt; ++kt) {                                           \
    const int cur = kt & 1;                                                    \
    if (kt + 1 < nkt) { GEMM_STAGE(cur ^ 1, kt + 1, A, BT, Kdim) }             \
    __builtin_amdgcn_s_setprio(1);                                             \
    _Pragma("unroll") for (int ks = 0; ks < 2; ++ks) {                         \
      bfrag af[4], bf[4];                                                      \
      _Pragma("unroll") for (int mt = 0; mt < 4; ++mt) {                       \
        int row = wr * 64 + mt * 16 + l15;                                     \
        int c = ks * 4 + l4;                                                   \
        af[mt] = *(const bfrag*)&Al[cur][row * 64 + ((c ^ (row & 7)) << 3)];   \
      }                                                                        \
      _Pragma("unroll") for (int nt = 0; nt < 4; ++nt) {                       \
        int row = wc * 64 + nt * 16 + l15;                                     \
        int c = ks * 4 + l4;                                                   \
        bf[nt] = *(const bfrag*)&Bl[cur][row * 64 + ((c ^ (row & 7)) << 3)];   \
      }                                                                        \
      _Pragma("unroll") for (int mt = 0; mt < 4; ++mt)                         \
          _Pragma("unroll") for (int nt = 0; nt < 4; ++nt)                     \
              acc[mt][nt] = __builtin_amdgcn_mfma_f32_16x16x32_bf16(           \
                  af[mt], bf[nt], acc[mt][nt], 0, 0, 0);                       \
    }                                                                          \
    __builtin_amdgcn_s_setprio(0);                                             \
    __syncthreads();                                                           \
  }

// Fused QKV projection: BT = [Wq^T; Wk^T; Wv^T] (2304 rows). Grid (M/128, 18).
// cols [0,2048) -> Qb row-major; [2048,2176) -> Kb; [2176,2304) -> Vtb transposed.
__global__ __launch_bounds__(256) void gemm_qkv(const short* __restrict__ A,
                                                const short* __restrict__ BT,
                                                const float* __restrict__ bq,
                                                const float* __restrict__ bk,
                                                const float* __restrict__ bv,
                                                unsigned short* __restrict__ Qb,
                                                unsigned short* __restrict__ Kb,
                                                unsigned short* __restrict__ Vtb,
                                                int M, int K) {
  __shared__ __align__(16) short Al[2][128 * 64];
  __shared__ __align__(16) short Bl[2][128 * 64];
  const int tid = threadIdx.x;
  const int w = tid >> 6, l = tid & 63;
  const int wr = w >> 1, wc = w & 1;
  const int l15 = l & 15, l4 = l >> 4;
  const int m0 = blockIdx.x * 128, n0 = blockIdx.y * 128;
  GEMM_PIPE_LOOP(A, BT, K)
#pragma unroll
  for (int mt = 0; mt < 4; ++mt) {
#pragma unroll
    for (int nt = 0; nt < 4; ++nt) {
#pragma unroll
      for (int r = 0; r < 4; ++r) {
        int row = m0 + wr * 64 + mt * 16 + l4 * 4 + r;
        int col = n0 + wc * 64 + nt * 16 + l15;
        if (col < HIDDEN) {
          Qb[(size_t)row * HIDDEN + col] = f2bf(acc[mt][nt][r] + bq[col]);
        } else if (col < HIDDEN + HDIM) {
          int lc = col - HIDDEN;
          Kb[(size_t)row * HDIM + lc] = f2bf(acc[mt][nt][r] + bk[lc]);
        } else {
          int lc = col - HIDDEN - HDIM;
          Vtb[(size_t)lc * M + row] = f2bf(acc[mt][nt][r] + bv[lc]);
        }
      }
    }
  }
}

// O-projection: f32 output C[row][col] = A*BT^T + bias.
__global__ __launch_bounds__(256) void gemm_out(const short* __restrict__ A,
                                                const short* __restrict__ BT,
                                                const float* __restrict__ bias,
                                                float* __restrict__ Cout,
                                                int M, int N, int K) {
  __shared__ __align__(16) short Al[2][128 * 64];
  __shared__ __align__(16) short Bl[2][128 * 64];
  const int tid = threadIdx.x;
  const int w = tid >> 6, l = tid & 63;
  const int wr = w >> 1, wc = w & 1;
  const int l15 = l & 15, l4 = l >> 4;
  const int m0 = blockIdx.x * 128, n0 = blockIdx.y * 128;
  GEMM_PIPE_LOOP(A, BT, K)
#pragma unroll
  for (int mt = 0; mt < 4; ++mt)
#pragma unroll
    for (int nt = 0; nt < 4; ++nt)
#pragma unroll
      for (int r = 0; r < 4; ++r) {
        int row = m0 + wr * 64 + mt * 16 + l4 * 4 + r;
        int col = n0 + wc * 64 + nt * 16 + l15;
        Cout[(size_t)row * N + col] = acc[mt][nt][r] + bias[col];
      }
}

// ---------------------------------------------------------------------------
// Flash attention, swapped QK^T, causal-paired blocks, 8 waves x 16 q-rows.
// Grid: (8, HEADS, B), 512 threads. Pass 0: q-tile x; pass 1: q-tile 15-x
// -> every block does exactly 34 KV-tiles of 64 keys. K,V^T dbuf in LDS.
__global__ __launch_bounds__(512, 1) void attn_kernel(const short* __restrict__ Q,
                                                      const short* __restrict__ Kg,
                                                      const short* __restrict__ Vt,
                                                      unsigned short* __restrict__ O) {
  __shared__ __align__(16) short Kl[2][64 * 128];  // [buf][key][d] swizzled
  __shared__ __align__(16) short Vl[2][128 * 64];  // [buf][d][key] swizzled
  __shared__ __align__(16) char Pl[8][2048];       // per-wave 16q x 64k bf16 swizzled
  const int tid = threadIdx.x;
  const int w = tid >> 6, l = tid & 63;
  const int l15 = l & 15, l4 = l >> 4;
  const int h = blockIdx.y, b = blockIdx.z;

#define STAGE_KV(buf, t)                                                            \
  do {                                                                              \
    const int kv0_ = (t) << 6;                                                      \
    _Pragma("unroll") for (int it = 0; it < 2; ++it) {                              \
      int bc = (w * 2 + it) * 64;                                                   \
      int C = bc + l;                                                               \
      int key = C >> 4, c = C & 15;                                                 \
      gl_lds16(Kg + (size_t)(b * SEQ + kv0_ + key) * HDIM + ((c ^ (key & 7)) << 3), \
               &Kl[buf][bc * 8]);                                                   \
    }                                                                               \
    _Pragma("unroll") for (int it = 0; it < 2; ++it) {                              \
      int bc = (w * 2 + it) * 64;                                                   \
      int C = bc + l;                                                               \
      int d = C >> 3, c = C & 7;                                                    \
      gl_lds16(Vt + (size_t)d * (BATCH * SEQ) + b * SEQ + kv0_ + ((c ^ (d & 7)) << 3), \
               &Vl[buf][bc * 8]);                                                   \
    }                                                                               \
  } while (0)

  for (int pass = 0; pass < 2; ++pass) {
    const int qtile = (pass == 0) ? (int)blockIdx.x : 15 - (int)blockIdx.x;
    const int q0 = qtile * 128;
    const int qw = q0 + w * 16;  // this wave's 16 q-rows [qw, qw+16)

    // Q fragments (B-operand: col=q=l15, k contiguous): 4 k-chunks of 32
    bfrag aq[4];
#pragma unroll
    for (int kk = 0; kk < 4; ++kk)
      aq[kk] = *(const bfrag*)(Q + (size_t)(b * SEQ + qw + l15) * HIDDEN +
                               h * HDIM + kk * 32 + l4 * 8);

    facc accO[8] = {};
    float mrow = -INFINITY, lrow = 0.f;
    const int nkv = (q0 + 128) >> 6;

    STAGE_KV(0, 0);
    __syncthreads();

    for (int t = 0; t < nkv; ++t) {
      const int cur = t & 1;
      if (t + 1 < nkv) STAGE_KV(cur ^ 1, t + 1);
      const int kv0 = t << 6;

      // S^T = K * Q^T : A-frag = K (row=key=l15), B-frag = Q (col=q=l15).
      // kk outer / kt inner -> MFMA dep distance 4 per sac chain.
      facc sac[4] = {};
      __builtin_amdgcn_s_setprio(1);
#pragma unroll
      for (int kk = 0; kk < 4; ++kk) {
        int c = kk * 4 + l4;
#pragma unroll
        for (int kt = 0; kt < 4; ++kt) {
          int key = kt * 16 + l15;
          bfrag ak = *(const bfrag*)&Kl[cur][key * 128 + ((c ^ (key & 7)) << 3)];
          sac[kt] = __builtin_amdgcn_mfma_f32_16x16x32_bf16(ak, aq[kk], sac[kt], 0, 0, 0);
        }
      }
      __builtin_amdgcn_s_setprio(0);

      // online softmax (base-2): lane holds 16 S values for q = l15
      const int qg = qw + l15;
      const bool needmask = (kv0 + 63 > qw);
      float p[4][4];
      float mt = -INFINITY;
#pragma unroll
      for (int kt = 0; kt < 4; ++kt)
#pragma unroll
        for (int r = 0; r < 4; ++r) {
          float v = sac[kt][r] * SCALE_L2E;
          if (needmask) {
            int keyg = kv0 + kt * 16 + l4 * 4 + r;
            v = (keyg <= qg) ? v : -INFINITY;
          }
          p[kt][r] = v;
          mt = fmaxf(mt, v);
        }
      mt = fmaxf(mt, __shfl_xor(mt, 16));
      mt = fmaxf(mt, __shfl_xor(mt, 32));
      float mn = fmaxf(mrow, mt);
      float f = exp2f(mrow - mn);
      mrow = mn;
      float ps = 0.f;
#pragma unroll
      for (int kt = 0; kt < 4; ++kt)
#pragma unroll
        for (int r = 0; r < 4; ++r) {
          p[kt][r] = exp2f(p[kt][r] - mn);
          ps += p[kt][r];
        }
      ps += __shfl_xor(ps, 16);
      ps += __shfl_xor(ps, 32);
      lrow = lrow * f + ps;
      float fr[4];
#pragma unroll
      for (int r = 0; r < 4; ++r) fr[r] = __shfl(f, l4 * 4 + r);

      // pack P^T -> P[q][key] bf16 in per-wave LDS (swizzled rows)
      char* pw = &Pl[w][0];
#pragma unroll
      for (int kt = 0; kt < 4; ++kt)
#pragma unroll
        for (int rp = 0; rp < 2; ++rp) {
          unsigned int u = ((unsigned int)f2bf(p[kt][2 * rp + 1]) << 16) | f2bf(p[kt][2 * rp]);
          int byte = (l15 * 128 + (kt * 16 + l4 * 4 + 2 * rp) * 2) ^ ((l15 & 7) << 4);
          *(unsigned int*)(pw + byte) = u;
        }
      // rescale O accumulator (rows q = l4*4+r)
#pragma unroll
      for (int nt = 0; nt < 8; ++nt)
#pragma unroll
        for (int r = 0; r < 4; ++r) accO[nt][r] *= fr[r];

      // PV: A = P[q][key] (row=q=l15), B = V^T row d (col=d=l15, k=key contig)
      __builtin_amdgcn_s_setprio(1);
#pragma unroll
      for (int kc = 0; kc < 2; ++kc) {
        bfrag pa = *(const bfrag*)(&Pl[w][0] +
                                   ((l15 * 128 + (kc * 32 + l4 * 8) * 2) ^ ((l15 & 7) << 4)));
#pragma unroll
        for (int nt = 0; nt < 8; ++nt) {
          int d = nt * 16 + l15;
          int cslot = (kc * 4 + l4) ^ (d & 7);
          bfrag bv = *(const bfrag*)&Vl[cur][d * 64 + (cslot << 3)];
          accO[nt] = __builtin_amdgcn_mfma_f32_16x16x32_bf16(pa, bv, accO[nt], 0, 0, 0);
        }
      }
      __builtin_amdgcn_s_setprio(0);
      __syncthreads();
    }

    // epilogue: O rows q = l4*4+r, cols d = nt*16+l15
    float inv = 1.f / lrow;
#pragma unroll
    for (int r = 0; r < 4; ++r) {
      float invr = __shfl(inv, l4 * 4 + r);
      int row = qw + l4 * 4 + r;
#pragma unroll
      for (int nt = 0; nt < 8; ++nt)
        O[(size_t)(b * SEQ + row) * HIDDEN + h * HDIM + nt * 16 + l15] =
            f2bf(accO[nt][r] * invr);
    }
  }
#undef STAGE_KV
}

// ---------------------------------------------------------------------------
extern "C" void kernel_launch(void* const* d_in, const int* in_sizes, int n_in,
                              void* d_out, int out_size, void* d_ws, size_t ws_size,
                              hipStream_t stream) {
  const float* x = (const float*)d_in[0];
  // d_in[1] = mask (causal, applied analytically)
  const float* Wq = (const float*)d_in[2];
  const float* bq = (const float*)d_in[3];
  const float* Wk = (const float*)d_in[4];
  const float* bk = (const float*)d_in[5];
  const float* Wv = (const float*)d_in[6];
  const float* bv = (const float*)d_in[7];
  const float* Wo = (const float*)d_in[8];
  const float* bo = (const float*)d_in[9];
  float* out = (float*)d_out;

  const size_t MS = (size_t)BATCH * SEQ;  // 4096
  char* ws = (char*)d_ws;
  short* xb = (short*)ws;      ws += MS * HIDDEN * 2;
  short* WqkvT = (short*)ws;   ws += (size_t)(HIDDEN + 2 * HDIM) * HIDDEN * 2;  // 2304 rows
  short* WoT = (short*)ws;     ws += (size_t)HIDDEN * HIDDEN * 2;
  short* Qb = (short*)ws;      ws += MS * HIDDEN * 2;
  short* Kb = (short*)ws;      ws += MS * HDIM * 2;
  short* Vtb = (short*)ws;     ws += (size_t)HDIM * MS * 2;
  short* Ab = (short*)ws;      ws += MS * HIDDEN * 2;

  cvt_bf16<<<(int)(MS * HIDDEN / 4 / 256), 256, 0, stream>>>(x, xb,
                                                             (int)(MS * HIDDEN / 4));
  transpose_cvt2<<<dim3(HIDDEN / 32, HIDDEN / 32, 2), 256, 0, stream>>>(
      Wq, WqkvT, Wo, WoT, HIDDEN, HIDDEN);
  transpose_cvt2<<<dim3(HDIM / 32, HIDDEN / 32, 2), 256, 0, stream>>>(
      Wk, WqkvT + (size_t)HIDDEN * HIDDEN, Wv, WqkvT + (size_t)(HIDDEN + HDIM) * HIDDEN,
      HIDDEN, HDIM);

  gemm_qkv<<<dim3(32, 18), 256, 0, stream>>>(xb, WqkvT, bq, bk, bv,
                                             (unsigned short*)Qb, (unsigned short*)Kb,
                                             (unsigned short*)Vtb, (int)MS, HIDDEN);

  attn_kernel<<<dim3(8, NHEADS, BATCH), 512, 0, stream>>>(Qb, Kb, Vtb,
                                                          (unsigned short*)Ab);

  gemm_out<<<dim3(32, 16), 256, 0, stream>>>(Ab, WoT, bo, out, (int)MS, HIDDEN, HIDDEN);
}

// Round 6
// 223.216 us; speedup vs baseline: 1.8325x; 1.0290x over previous
//
#include <hip/hip_runtime.h>

// ---------------------------------------------------------------------------
// MultiQueryAttention: out = softmax_causal((xWq+bq)(xWk+bk)^T * scale) (xWv+bv) Wo + bo
// B=2, S=2048, HIDDEN=2048, HEADS=16 (multi-query: 1 KV head), HEAD_DIM=128
// R5: attn -> v_cvt_pk_bf16_f32 for P-pack (kills ~96 VALU ops/tile/wave);
//     QBLK=64, 4 waves, 72KB LDS -> 2 blocks/CU (grid 512, pairing over 32).
//     GEMMs unchanged (R4 2-phase pipeline).
// ---------------------------------------------------------------------------

#define HIDDEN 2048
#define NHEADS 16
#define HDIM 128
#define BATCH 2
#define SEQ 2048
// SCALE_QK * log2(e): softmax computed in base-2 (exp2), exactly equivalent.
#define SCALE_L2E 0.1275258653864023f

typedef __attribute__((ext_vector_type(8))) short bfrag;   // 8 bf16 (4 VGPRs)
typedef __attribute__((ext_vector_type(4))) float facc;    // MFMA accumulator

__device__ __forceinline__ unsigned short f2bf(float f) {  // f32 -> bf16 RNE
  unsigned int u = __float_as_uint(f);
  u += 0x7fffu + ((u >> 16) & 1u);
  return (unsigned short)(u >> 16);
}

// HW packed f32x2 -> bf16x2 (RNE); no builtin on gfx950, inline asm (T12).
__device__ __forceinline__ unsigned int cvt_pk_bf16(float lo, float hi) {
  unsigned int r;
  asm("v_cvt_pk_bf16_f32 %0, %1, %2" : "=v"(r) : "v"(lo), "v"(hi));
  return r;
}

// async global->LDS, 16B per lane. LDS dest is WAVE-UNIFORM base (+lane*16 by HW).
__device__ __forceinline__ void gl_lds16(const void* g, void* l) {
  __builtin_amdgcn_global_load_lds(
      (const __attribute__((address_space(1))) void*)g,
      (__attribute__((address_space(3))) void*)l, 16, 0, 0);
}

// ---------------------------------------------------------------------------
// x f32 -> bf16 (vectorized, HW cvt_pk)
__global__ __launch_bounds__(256) void cvt_bf16(const float* __restrict__ in,
                                                unsigned int* __restrict__ out, int n4) {
  int i = blockIdx.x * 256 + threadIdx.x;
  if (i >= n4) return;
  float4 v = ((const float4*)in)[i];
  uint2 o = {cvt_pk_bf16(v.x, v.y), cvt_pk_bf16(v.z, v.w)};
  ((uint2*)out)[i] = o;
}

// Two weights per launch (blockIdx.z picks): W [K][N] f32 -> WT [N][K] bf16.
__global__ __launch_bounds__(256) void transpose_cvt2(const float* __restrict__ W0,
                                                      short* __restrict__ T0,
                                                      const float* __restrict__ W1,
                                                      short* __restrict__ T1,
                                                      int K, int N) {
  const float* W = blockIdx.z ? W1 : W0;
  short* WT = blockIdx.z ? T1 : T0;
  __shared__ float t[32][33];
  int tx = threadIdx.x & 31, ty = threadIdx.x >> 5;
  int n0 = blockIdx.x * 32, k0 = blockIdx.y * 32;
#pragma unroll
  for (int j = 0; j < 4; ++j)
    t[ty + j * 8][tx] = W[(size_t)(k0 + ty + j * 8) * N + n0 + tx];
  __syncthreads();
#pragma unroll
  for (int j = 0; j < 4; ++j)
    WT[(size_t)(n0 + ty + j * 8) * K + k0 + tx] = (short)f2bf(t[tx][ty + j * 8]);
}

// ---------------------------------------------------------------------------
// 2-phase pipelined GEMM main loop: 128x128 tile, BK=64, double-buffered LDS.
#define GEMM_STAGE(buf, kt, A, BT, Kdim)                                       \
  _Pragma("unroll") for (int it = 0; it < 4; ++it) {                           \
    int bc = (w * 4 + it) * 64;                                                \
    int C = bc + l;                                                            \
    int row = C >> 3, c = C & 7;                                               \
    int gofs = (kt) * 64 + ((c ^ (row & 7)) << 3);                             \
    gl_lds16((A) + (size_t)(m0 + row) * (Kdim) + gofs, &Al[buf][bc * 8]);      \
    gl_lds16((BT) + (size_t)(n0 + row) * (Kdim) + gofs, &Bl[buf][bc * 8]);     \
  }

#define GEMM_PIPE_LOOP(A, BT, Kdim)                                            \
  facc acc[4][4] = {};                                                         \
  const int nkt = (Kdim) >> 6;                                                 \
  GEMM_STAGE(0, 0, A, BT, Kdim)                                                \
  __syncthreads();                                                             \
  for (int kt = 0; kt < nkt; ++kt) {                                           \
    const int cur = kt & 1;                                                    \
    if (kt + 1 < nkt) { GEMM_STAGE(cur ^ 1, kt + 1, A, BT, Kdim) }             \
    __builtin_amdgcn_s_setprio(1);                                             \
    _Pragma("unroll") for (int ks = 0; ks < 2; ++ks) {                         \
      bfrag af[4], bf[4];                                                      \
      _Pragma("unroll") for (int mt = 0; mt < 4; ++mt) {                       \
        int row = wr * 64 + mt * 16 + l15;                                     \
        int c = ks * 4 + l4;                                                   \
        af[mt] = *(const bfrag*)&Al[cur][row * 64 + ((c ^ (row & 7)) << 3)];   \
      }                                                                        \
      _Pragma("unroll") for (int nt = 0; nt < 4; ++nt) {                       \
        int row = wc * 64 + nt * 16 + l15;                                     \
        int c = ks * 4 + l4;                                                   \
        bf[nt] = *(const bfrag*)&Bl[cur][row * 64 + ((c ^ (row & 7)) << 3)];   \
      }                                                                        \
      _Pragma("unroll") for (int mt = 0; mt < 4; ++mt)                         \
          _Pragma("unroll") for (int nt = 0; nt < 4; ++nt)                     \
              acc[mt][nt] = __builtin_amdgcn_mfma_f32_16x16x32_bf16(           \
                  af[mt], bf[nt], acc[mt][nt], 0, 0, 0);                       \
    }                                                                          \
    __builtin_amdgcn_s_setprio(0);                                             \
    __syncthreads();                                                           \
  }

// Fused QKV projection: BT = [Wq^T; Wk^T; Wv^T] (2304 rows). Grid (M/128, 18).
__global__ __launch_bounds__(256) void gemm_qkv(const short* __restrict__ A,
                                                const short* __restrict__ BT,
                                                const float* __restrict__ bq,
                                                const float* __restrict__ bk,
                                                const float* __restrict__ bv,
                                                unsigned short* __restrict__ Qb,
                                                unsigned short* __restrict__ Kb,
                                                unsigned short* __restrict__ Vtb,
                                                int M, int K) {
  __shared__ __align__(16) short Al[2][128 * 64];
  __shared__ __align__(16) short Bl[2][128 * 64];
  const int tid = threadIdx.x;
  const int w = tid >> 6, l = tid & 63;
  const int wr = w >> 1, wc = w & 1;
  const int l15 = l & 15, l4 = l >> 4;
  const int m0 = blockIdx.x * 128, n0 = blockIdx.y * 128;
  GEMM_PIPE_LOOP(A, BT, K)
#pragma unroll
  for (int mt = 0; mt < 4; ++mt) {
#pragma unroll
    for (int nt = 0; nt < 4; ++nt) {
#pragma unroll
      for (int r = 0; r < 4; ++r) {
        int row = m0 + wr * 64 + mt * 16 + l4 * 4 + r;
        int col = n0 + wc * 64 + nt * 16 + l15;
        if (col < HIDDEN) {
          Qb[(size_t)row * HIDDEN + col] = f2bf(acc[mt][nt][r] + bq[col]);
        } else if (col < HIDDEN + HDIM) {
          int lc = col - HIDDEN;
          Kb[(size_t)row * HDIM + lc] = f2bf(acc[mt][nt][r] + bk[lc]);
        } else {
          int lc = col - HIDDEN - HDIM;
          Vtb[(size_t)lc * M + row] = f2bf(acc[mt][nt][r] + bv[lc]);
        }
      }
    }
  }
}

// O-projection: f32 output C[row][col] = A*BT^T + bias.
__global__ __launch_bounds__(256) void gemm_out(const short* __restrict__ A,
                                                const short* __restrict__ BT,
                                                const float* __restrict__ bias,
                                                float* __restrict__ Cout,
                                                int M, int N, int K) {
  __shared__ __align__(16) short Al[2][128 * 64];
  __shared__ __align__(16) short Bl[2][128 * 64];
  const int tid = threadIdx.x;
  const int w = tid >> 6, l = tid & 63;
  const int wr = w >> 1, wc = w & 1;
  const int l15 = l & 15, l4 = l >> 4;
  const int m0 = blockIdx.x * 128, n0 = blockIdx.y * 128;
  GEMM_PIPE_LOOP(A, BT, K)
#pragma unroll
  for (int mt = 0; mt < 4; ++mt)
#pragma unroll
    for (int nt = 0; nt < 4; ++nt)
#pragma unroll
      for (int r = 0; r < 4; ++r) {
        int row = m0 + wr * 64 + mt * 16 + l4 * 4 + r;
        int col = n0 + wc * 64 + nt * 16 + l15;
        Cout[(size_t)row * N + col] = acc[mt][nt][r] + bias[col];
      }
}

// ---------------------------------------------------------------------------
// Flash attention, swapped QK^T, causal-paired blocks, 4 waves x 16 q-rows
// (QBLK=64). Grid: (16, HEADS, B) = 512 blocks, 256 threads, 72KB LDS ->
// 2 blocks/CU (independent barrier domains overlap each other's stalls).
// Pass 0: q-tile x; pass 1: q-tile 31-x -> exactly 33 KV-tiles of 64 keys.
__global__ __launch_bounds__(256, 2) void attn_kernel(const short* __restrict__ Q,
                                                      const short* __restrict__ Kg,
                                                      const short* __restrict__ Vt,
                                                      unsigned short* __restrict__ O) {
  __shared__ __align__(16) short Kl[2][64 * 128];  // [buf][key][d] swizzled
  __shared__ __align__(16) short Vl[2][128 * 64];  // [buf][d][key] swizzled
  __shared__ __align__(16) char Pl[4][2048];       // per-wave 16q x 64k bf16 swizzled
  const int tid = threadIdx.x;
  const int w = tid >> 6, l = tid & 63;
  const int l15 = l & 15, l4 = l >> 4;
  const int h = blockIdx.y, b = blockIdx.z;

  // K tile: rows of 16 chunks (key=C>>4). V tile: rows of 8 chunks (d=C>>3).
  // 256 threads -> 4 chunks each per tile. Source pre-swizzled (involution).
#define STAGE_KV(buf, t)                                                            \
  do {                                                                              \
    const int kv0_ = (t) << 6;                                                      \
    _Pragma("unroll") for (int it = 0; it < 4; ++it) {                              \
      int bc = (w * 4 + it) * 64;                                                   \
      int C = bc + l;                                                               \
      int key = C >> 4, c = C & 15;                                                 \
      gl_lds16(Kg + (size_t)(b * SEQ + kv0_ + key) * HDIM + ((c ^ (key & 7)) << 3), \
               &Kl[buf][bc * 8]);                                                   \
    }                                                                               \
    _Pragma("unroll") for (int it = 0; it < 4; ++it) {                              \
      int bc = (w * 4 + it) * 64;                                                   \
      int C = bc + l;                                                               \
      int d = C >> 3, c = C & 7;                                                    \
      gl_lds16(Vt + (size_t)d * (BATCH * SEQ) + b * SEQ + kv0_ + ((c ^ (d & 7)) << 3), \
               &Vl[buf][bc * 8]);                                                   \
    }                                                                               \
  } while (0)

  for (int pass = 0; pass < 2; ++pass) {
    const int qtile = (pass == 0) ? (int)blockIdx.x : 31 - (int)blockIdx.x;
    const int q0 = qtile * 64;
    const int qw = q0 + w * 16;  // this wave's 16 q-rows [qw, qw+16)

    // Q fragments (B-operand: col=q=l15, k contiguous): 4 k-chunks of 32
    bfrag aq[4];
#pragma unroll
    for (int kk = 0; kk < 4; ++kk)
      aq[kk] = *(const bfrag*)(Q + (size_t)(b * SEQ + qw + l15) * HIDDEN +
                               h * HDIM + kk * 32 + l4 * 8);

    facc accO[8] = {};
    float mrow = -INFINITY, lrow = 0.f;
    const int nkv = qtile + 1;

    STAGE_KV(0, 0);
    __syncthreads();

    for (int t = 0; t < nkv; ++t) {
      const int cur = t & 1;
      if (t + 1 < nkv) STAGE_KV(cur ^ 1, t + 1);
      const int kv0 = t << 6;

      // S^T = K * Q^T : A-frag = K (row=key=l15), B-frag = Q (col=q=l15).
      // kk outer / kt inner -> MFMA dep distance 4 per sac chain.
      facc sac[4] = {};
      __builtin_amdgcn_s_setprio(1);
#pragma unroll
      for (int kk = 0; kk < 4; ++kk) {
        int c = kk * 4 + l4;
#pragma unroll
        for (int kt = 0; kt < 4; ++kt) {
          int key = kt * 16 + l15;
          bfrag ak = *(const bfrag*)&Kl[cur][key * 128 + ((c ^ (key & 7)) << 3)];
          sac[kt] = __builtin_amdgcn_mfma_f32_16x16x32_bf16(ak, aq[kk], sac[kt], 0, 0, 0);
        }
      }
      __builtin_amdgcn_s_setprio(0);

      // online softmax (base-2): lane holds 16 S values for q = l15
      const int qg = qw + l15;
      const bool needmask = (kv0 + 63 > qw);
      float p[4][4];
      float mt = -INFINITY;
#pragma unroll
      for (int kt = 0; kt < 4; ++kt)
#pragma unroll
        for (int r = 0; r < 4; ++r) {
          float v = sac[kt][r] * SCALE_L2E;
          if (needmask) {
            int keyg = kv0 + kt * 16 + l4 * 4 + r;
            v = (keyg <= qg) ? v : -INFINITY;
          }
          p[kt][r] = v;
          mt = fmaxf(mt, v);
        }
      mt = fmaxf(mt, __shfl_xor(mt, 16));
      mt = fmaxf(mt, __shfl_xor(mt, 32));
      float mn = fmaxf(mrow, mt);
      float f = exp2f(mrow - mn);
      mrow = mn;
      float ps = 0.f;
#pragma unroll
      for (int kt = 0; kt < 4; ++kt)
#pragma unroll
        for (int r = 0; r < 4; ++r) {
          p[kt][r] = exp2f(p[kt][r] - mn);
          ps += p[kt][r];
        }
      ps += __shfl_xor(ps, 16);
      ps += __shfl_xor(ps, 32);
      lrow = lrow * f + ps;
      float fr[4];
#pragma unroll
      for (int r = 0; r < 4; ++r) fr[r] = __shfl(f, l4 * 4 + r);

      // pack P^T -> P[q][key] bf16 in per-wave LDS (swizzled rows), HW cvt_pk
      char* pw = &Pl[w][0];
#pragma unroll
      for (int kt = 0; kt < 4; ++kt)
#pragma unroll
        for (int rp = 0; rp < 2; ++rp) {
          unsigned int u = cvt_pk_bf16(p[kt][2 * rp], p[kt][2 * rp + 1]);
          int byte = (l15 * 128 + (kt * 16 + l4 * 4 + 2 * rp) * 2) ^ ((l15 & 7) << 4);
          *(unsigned int*)(pw + byte) = u;
        }
      // rescale O accumulator (rows q = l4*4+r)
#pragma unroll
      for (int nt = 0; nt < 8; ++nt)
#pragma unroll
        for (int r = 0; r < 4; ++r) accO[nt][r] *= fr[r];

      // PV: A = P[q][key] (row=q=l15), B = V^T row d (col=d=l15, k=key contig)
      __builtin_amdgcn_s_setprio(1);
#pragma unroll
      for (int kc = 0; kc < 2; ++kc) {
        bfrag pa = *(const bfrag*)(&Pl[w][0] +
                                   ((l15 * 128 + (kc * 32 + l4 * 8) * 2) ^ ((l15 & 7) << 4)));
#pragma unroll
        for (int nt = 0; nt < 8; ++nt) {
          int d = nt * 16 + l15;
          int cslot = (kc * 4 + l4) ^ (d & 7);
          bfrag bv = *(const bfrag*)&Vl[cur][d * 64 + (cslot << 3)];
          accO[nt] = __builtin_amdgcn_mfma_f32_16x16x32_bf16(pa, bv, accO[nt], 0, 0, 0);
        }
      }
      __builtin_amdgcn_s_setprio(0);
      __syncthreads();
    }

    // epilogue: O rows q = l4*4+r, cols d = nt*16+l15
    float inv = 1.f / lrow;
#pragma unroll
    for (int r = 0; r < 4; ++r) {
      float invr = __shfl(inv, l4 * 4 + r);
      int row = qw + l4 * 4 + r;
#pragma unroll
      for (int nt = 0; nt < 8; ++nt)
        O[(size_t)(b * SEQ + row) * HIDDEN + h * HDIM + nt * 16 + l15] =
            f2bf(accO[nt][r] * invr);
    }
  }
#undef STAGE_KV
}

// ---------------------------------------------------------------------------
extern "C" void kernel_launch(void* const* d_in, const int* in_sizes, int n_in,
                              void* d_out, int out_size, void* d_ws, size_t ws_size,
                              hipStream_t stream) {
  const float* x = (const float*)d_in[0];
  // d_in[1] = mask (causal, applied analytically)
  const float* Wq = (const float*)d_in[2];
  const float* bq = (const float*)d_in[3];
  const float* Wk = (const float*)d_in[4];
  const float* bk = (const float*)d_in[5];
  const float* Wv = (const float*)d_in[6];
  const float* bv = (const float*)d_in[7];
  const float* Wo = (const float*)d_in[8];
  const float* bo = (const float*)d_in[9];
  float* out = (float*)d_out;

  const size_t MS = (size_t)BATCH * SEQ;  // 4096
  char* ws = (char*)d_ws;
  short* xb = (short*)ws;      ws += MS * HIDDEN * 2;
  short* WqkvT = (short*)ws;   ws += (size_t)(HIDDEN + 2 * HDIM) * HIDDEN * 2;  // 2304 rows
  short* WoT = (short*)ws;     ws += (size_t)HIDDEN * HIDDEN * 2;
  short* Qb = (short*)ws;      ws += MS * HIDDEN * 2;
  short* Kb = (short*)ws;      ws += MS * HDIM * 2;
  short* Vtb = (short*)ws;     ws += (size_t)HDIM * MS * 2;
  short* Ab = (short*)ws;      ws += MS * HIDDEN * 2;

  cvt_bf16<<<(int)(MS * HIDDEN / 4 / 256), 256, 0, stream>>>(
      x, (unsigned int*)xb, (int)(MS * HIDDEN / 4));
  transpose_cvt2<<<dim3(HIDDEN / 32, HIDDEN / 32, 2), 256, 0, stream>>>(
      Wq, WqkvT, Wo, WoT, HIDDEN, HIDDEN);
  transpose_cvt2<<<dim3(HDIM / 32, HIDDEN / 32, 2), 256, 0, stream>>>(
      Wk, WqkvT + (size_t)HIDDEN * HIDDEN, Wv, WqkvT + (size_t)(HIDDEN + HDIM) * HIDDEN,
      HIDDEN, HDIM);

  gemm_qkv<<<dim3(32, 18), 256, 0, stream>>>(xb, WqkvT, bq, bk, bv,
                                             (unsigned short*)Qb, (unsigned short*)Kb,
                                             (unsigned short*)Vtb, (int)MS, HIDDEN);

  attn_kernel<<<dim3(16, NHEADS, BATCH), 256, 0, stream>>>(Qb, Kb, Vtb,
                                                           (unsigned short*)Ab);

  gemm_out<<<dim3(32, 16), 256, 0, stream>>>(Ab, WoT, bo, out, (int)MS, HIDDEN, HIDDEN);
}